// Round 11
// baseline (20213.789 us; speedup 1.0000x reference)
//
#include <hip/hip_runtime.h>
#include <stdint.h>

#define N_PTS   65536
#define N_GRP   1024
#define K_NB    32
#define F_DIM   64

// ---- FPS (single block, lazy chunk-pruned) ----
#define FPS1_THR 1024
#define NCHUNK   1024
#define CPTS     64
#define NBINS    4096        // 16x16x16 morton grid

// ---- fallback FPS (R1-proven agent-scope), only if ws too small ----
#define F2_BLOCKS 16
#define F2_THR    512
#define F2_TT     (F2_BLOCKS*F2_THR)
#define F2_P      (N_PTS / F2_TT)

// ---------- helpers ----------
__device__ __forceinline__ unsigned long long packMinKey(float v, unsigned int idx) {
  unsigned int b = __float_as_uint(v);
  b = (b & 0x80000000u) ? ~b : (b | 0x80000000u);
  return ((unsigned long long)b << 32) | idx;
}
__device__ __forceinline__ float unpackMinVal(unsigned long long k) {
  unsigned int b = (unsigned int)(k >> 32);
  b = (b & 0x80000000u) ? (b & 0x7FFFFFFFu) : ~b;
  return __uint_as_float(b);
}
__device__ __forceinline__ unsigned spread4(unsigned b) {
  return (b & 1u) | ((b & 2u) << 2) | ((b & 4u) << 4) | ((b & 8u) << 6);
}
__device__ __forceinline__ unsigned morton_bid(float a, float b, float c) {
  const float S = 16.0f / 11.0f;
  int bx = (int)((a + 5.5f) * S);
  int by = (int)((b + 5.5f) * S);
  int bz = (int)((c + 5.5f) * S);
  bx = min(max(bx, 0), 15); by = min(max(by, 0), 15); bz = min(max(bz, 0), 15);
  return spread4((unsigned)bx) | (spread4((unsigned)by) << 1) | (spread4((unsigned)bz) << 2);
}
// key = dist_bits[63:32] | (0xFFFF-orig)[31:16] | chunk[9:0]; sign bit 0, NaN impossible
// -> u64 order == f64 order; reduce with v_max_f64.
__device__ __forceinline__ unsigned long long packCKey(float d, unsigned orig, int c) {
  return ((unsigned long long)__float_as_uint(d) << 32)
       | ((unsigned long long)(0xFFFFu - (orig & 0xFFFFu)) << 16)
       | (unsigned long long)(unsigned)c;
}

// ---------- Phase 1: FPS — one block; lazy rescan-on-demand ----------
__global__ void __launch_bounds__(FPS1_THR)
fps_kernel(const float* __restrict__ x, float4* __restrict__ xs4,
           float* __restrict__ dd, float* __restrict__ centers)
{
  __shared__ __align__(16) char smem[81920];
  unsigned long long* ckeys = (unsigned long long*)(smem + 0);   // 8K  chunk key upper bounds
  float* bxl = (float*)(smem + 8192);                            // bbox arrays (persistent)
  float* bxh = (float*)(smem + 12288);
  float* byl = (float*)(smem + 16384);
  float* byh = (float*)(smem + 20480);
  float* bzl = (float*)(smem + 24576);
  float* bzh = (float*)(smem + 28672);
  float* scx = (float*)(smem + 32768);                           // centers list (persistent)
  float* scy = (float*)(smem + 36864);
  float* scz = (float*)(smem + 40960);
  int*   slr = (int*)(smem + 45056);                             // #centers applied per chunk
  unsigned* sA = (unsigned*)(smem + 49152);                      // scan ping (transient)
  unsigned* sB = (unsigned*)(smem + 65536);                      // scan pong (transient)
  __shared__ double redd[16];

  const int tid = threadIdx.x, lane = tid & 63, wid = tid >> 6;

  // ---- histogram
#pragma unroll
  for (int j = 0; j < NBINS/FPS1_THR; ++j) sA[tid + j*FPS1_THR] = 0u;
  __syncthreads();
  for (int i = tid; i < N_PTS; i += FPS1_THR) {
    float a = x[i*3+0], b = x[i*3+1], c = x[i*3+2];
    atomicAdd(&sA[morton_bid(a,b,c)], 1u);
  }
  __syncthreads();

  // ---- inclusive scan (ping-pong) -> sA; exclusive cursors -> sB
  {
    unsigned* src = sA; unsigned* dst = sB;
    for (int off = 1; off < NBINS; off <<= 1) {
#pragma unroll
      for (int j = 0; j < NBINS/FPS1_THR; ++j) {
        int i = tid + j*FPS1_THR;
        unsigned v = src[i];
        if (i >= off) v += src[i-off];
        dst[i] = v;
      }
      __syncthreads();
      unsigned* t_ = src; src = dst; dst = t_;
    }
#pragma unroll
    for (int j = 0; j < NBINS/FPS1_THR; ++j) {
      int i = tid + j*FPS1_THR;
      sB[i] = (i == 0) ? 0u : sA[i-1];
    }
    __syncthreads();
  }

  // ---- scatter (chunk-major [c][k])
  for (int i = tid; i < N_PTS; i += FPS1_THR) {
    float a = x[i*3+0], b = x[i*3+1], c = x[i*3+2];
    unsigned pos = atomicAdd(&sB[morton_bid(a,b,c)], 1u);
    xs4[pos] = make_float4(a, b, c, __uint_as_float((unsigned)i));
  }
  __syncthreads();

  // ---- c_0 = x[0]
  const float c0x = x[0], c0y = x[1], c0z = x[2];
  if (tid == 0) {
    centers[0] = c0x; centers[1] = c0y; centers[2] = c0z;
    scx[0] = c0x; scy[0] = c0y; scz[0] = c0z;
  }

  // ---- per-chunk: bbox + eager apply c_0 + exact key + lr=1
  for (int cc = 0; cc < 64; ++cc) {
    const int c = wid*64 + cc;
    float4 f = xs4[c*CPTS + lane];
    float xl = f.x, xh = f.x, yl = f.y, yh = f.y, zl = f.z, zh = f.z;
#pragma unroll
    for (int off = 32; off; off >>= 1) {
      xl = fminf(xl, __shfl_xor(xl, off)); xh = fmaxf(xh, __shfl_xor(xh, off));
      yl = fminf(yl, __shfl_xor(yl, off)); yh = fmaxf(yh, __shfl_xor(yh, off));
      zl = fminf(zl, __shfl_xor(zl, off)); zh = fmaxf(zh, __shfl_xor(zh, off));
    }
    float e0 = f.x - c0x, e1 = f.y - c0y, e2 = f.z - c0z;
    float dist = fmaf(e2,e2, fmaf(e1,e1, e0*e0));     // proven chain
    float dn = fminf(1e10f, dist);                    // INIT_DIST min (exact)
    dd[c*CPTS + lane] = dn;
    double kd = __longlong_as_double((long long)packCKey(dn, __float_as_uint(f.w), c));
#pragma unroll
    for (int off = 32; off; off >>= 1) kd = fmax(kd, __shfl_xor(kd, off));
    if (lane == 0) {
      ckeys[c] = (unsigned long long)__double_as_longlong(kd);
      slr[c] = 1;
      bxl[c]=xl; bxh[c]=xh; byl[c]=yl; byh[c]=yh; bzl[c]=zl; bzh[c]=zh;
    }
  }
  __syncthreads();
  const float rxl = bxl[tid], rxh = bxh[tid];
  const float ryl = byl[tid], ryh = byh[tid];
  const float rzl = bzl[tid], rzh = bzh[tid];

  // ---- rounds: lazy verify loop
  for (int r = 1; r < N_GRP; ++r) {
    unsigned long long key;
    for (;;) {
      __syncthreads();                                 // S1: ckeys/slr stable
      double kd = __longlong_as_double((long long)ckeys[tid]);
#pragma unroll
      for (int off = 32; off; off >>= 1) kd = fmax(kd, __shfl_xor(kd, off));
      if (lane == 0) redd[wid] = kd;
      __syncthreads();                                 // S2: redd ready
      double k2 = redd[lane & 15];
#pragma unroll
      for (int off = 1; off < 16; off <<= 1) k2 = fmax(k2, __shfl_xor(k2, off));
      key = (unsigned long long)__double_as_longlong(k2);
      const int cstar = (int)(key & 1023ull);
      const int fr = slr[cstar];                       // broadcast read, uniform
      __syncthreads();                                 // S3: lr reads done before rescan writes
      if (fr >= r) break;                              // key exact -> emit
      if (wid == 0) {
        // rescan cstar: apply pending centers fr..r-1 (bbox-filtered), wave0 only
        const int sidx = cstar*CPTS + lane;
        float4 f = xs4[sidx];
        float dk = dd[sidx];
        const float XL = bxl[cstar], XH = bxh[cstar];
        const float YL = byl[cstar], YH = byh[cstar];
        const float ZL = bzl[cstar], ZH = bzh[cstar];
        const float cdm = __uint_as_float((unsigned)(ckeys[cstar] >> 32)) * 1.0001f;
        for (int j0 = fr; j0 < r; j0 += 64) {
          const int j = j0 + lane;
          bool act = false;
          if (j < r) {
            float ax = scx[j], ay = scy[j], az = scz[j];
            float dxl = fmaxf(fmaxf(XL - ax, ax - XH), 0.0f);
            float dyl = fmaxf(fmaxf(YL - ay, ay - YH), 0.0f);
            float dzl = fmaxf(fmaxf(ZL - az, az - ZH), 0.0f);
            float b2 = fmaf(dzl, dzl, fmaf(dyl, dyl, dxl*dxl));
            act = b2 < cdm;                            // conservative (old cdm): exact-safe
          }
          unsigned long long bal = __ballot(act);
          while (bal) {
            const int jj = j0 + (__ffsll((unsigned long long)bal) - 1);
            bal &= bal - 1;
            float ax = scx[jj], ay = scy[jj], az = scz[jj];
            float e0 = f.x - ax, e1 = f.y - ay, e2 = f.z - az;
            float dist = fmaf(e2,e2, fmaf(e1,e1, e0*e0));   // proven chain
            dk = fminf(dk, dist);                      // fp-min: order-exact
          }
        }
        dd[sidx] = dk;
        double kd2 = __longlong_as_double((long long)packCKey(dk, __float_as_uint(f.w), cstar));
#pragma unroll
        for (int off = 32; off; off >>= 1) kd2 = fmax(kd2, __shfl_xor(kd2, off));
        if (lane == 0) {
          ckeys[cstar] = (unsigned long long)__double_as_longlong(kd2);
          slr[cstar] = r;                              // fresh now
        }
      }
    }
    // ---- emit winner r
    const unsigned orig = 0xFFFFu - (unsigned)((key >> 16) & 0xFFFFull);
    const float wx = x[orig*3+0], wy = x[orig*3+1], wz = x[orig*3+2];  // broadcast load
    if (tid == 0) {
      centers[r*3+0] = wx; centers[r*3+1] = wy; centers[r*3+2] = wz;
      scx[r] = wx; scy[r] = wy; scz[r] = wz;
    }
    // ---- A': consume c_r for own chunk when provably unaffected (proven inequality)
    if (slr[tid] == r) {
      const float cdm = __uint_as_float((unsigned)(ckeys[tid] >> 32));
      float dxl = fmaxf(fmaxf(rxl - wx, wx - rxh), 0.0f);
      float dyl = fmaxf(fmaxf(ryl - wy, wy - ryh), 0.0f);
      float dzl = fmaxf(fmaxf(rzl - wz, wz - rzh), 0.0f);
      float b2 = fmaf(dzl, dzl, fmaf(dyl, dyl, dxl*dxl));
      if (!(b2 < cdm * 1.0001f)) slr[tid] = r + 1;     // key provably unchanged by c_r
    }
  }
}

// ---------- fallback FPS (only if ws too small) ----------
__global__ void __launch_bounds__(F2_THR)
fps_safe_kernel(const float* __restrict__ x, unsigned long long* __restrict__ slots,
                unsigned int* __restrict__ cnts, float* __restrict__ centers)
{
  __shared__ unsigned long long red[F2_THR/64];
  const int t = blockIdx.x * F2_THR + threadIdx.x;
  float px[F2_P], py[F2_P], pz[F2_P], d[F2_P];
#pragma unroll
  for (int k = 0; k < F2_P; ++k) {
    int p = t + k * F2_TT;
    px[k] = x[p*3+0]; py[k] = x[p*3+1]; pz[k] = x[p*3+2];
    d[k] = 1e10f;
  }
  float cx = x[0], cy = x[1], cz = x[2];
  if (blockIdx.x == 0 && threadIdx.x == 0) {
    centers[0] = cx; centers[1] = cy; centers[2] = cz;
  }
  for (int r = 1; r < N_GRP; ++r) {
    unsigned long long best = 0ull;
#pragma unroll
    for (int k = 0; k < F2_P; ++k) {
      float e0 = px[k]-cx, e1 = py[k]-cy, e2 = pz[k]-cz;
      float dist = fmaf(e2,e2, fmaf(e1,e1, e0*e0));
      float dn = fminf(d[k], dist);
      d[k] = dn;
      unsigned long long pk = ((unsigned long long)__float_as_uint(dn) << 32)
                            | (0xFFFFFFFFu - (unsigned)(t + k*F2_TT));
      if (pk > best) best = pk;
    }
#pragma unroll
    for (int off = 32; off; off >>= 1) {
      unsigned long long o = __shfl_down(best, off);
      if (o > best) best = o;
    }
    const int wid = threadIdx.x >> 6;
    if ((threadIdx.x & 63) == 0) red[wid] = best;
    __syncthreads();
    if (threadIdx.x == 0) {
#pragma unroll
      for (int w = 1; w < F2_THR/64; ++w) if (red[w] > best) best = red[w];
      atomicMax(&slots[r], best);
      __hip_atomic_fetch_add(&cnts[r], 1u, __ATOMIC_RELEASE, __HIP_MEMORY_SCOPE_AGENT);
      while (__hip_atomic_load(&cnts[r], __ATOMIC_ACQUIRE, __HIP_MEMORY_SCOPE_AGENT) < F2_BLOCKS)
        __builtin_amdgcn_s_sleep(1);
      red[0] = __hip_atomic_load(&slots[r], __ATOMIC_RELAXED, __HIP_MEMORY_SCOPE_AGENT);
    }
    __syncthreads();
    const unsigned long long win = red[0];
    const int widx = (int)(0xFFFFFFFFu - (unsigned int)(win & 0xFFFFFFFFull));
    cx = x[widx*3+0]; cy = x[widx*3+1]; cz = x[widx*3+2];
    if (blockIdx.x == 0 && threadIdx.x == 0) {
      centers[r*3+0] = cx; centers[r*3+1] = cy; centers[r*3+2] = cz;
    }
    __syncthreads();
  }
}

// ---------- Phase 2: per-group exact 32 smallest (proven) ----------
#define TKT 256
#define CAP 3072

__global__ void __launch_bounds__(TKT)
topk_kernel(const float* __restrict__ x, const float* __restrict__ feat,
            const float* __restrict__ centers, float* __restrict__ out)
{
  __shared__ float cv[CAP];
  __shared__ int   ci[CAP];
  __shared__ int   s_cnt;
  __shared__ float s_thr;
  __shared__ float selv[K_NB];
  __shared__ int   seli[K_NB];

  const int g = blockIdx.x, tid = threadIdx.x;
  const float cx = centers[g*3+0], cy = centers[g*3+1], cz = centers[g*3+2];
  const float c2 = fmaf(cz,cz, fmaf(cy,cy, cx*cx));
  if (tid == 0) { s_cnt = 0; s_thr = __builtin_inff(); }
  __syncthreads();

  const int CH = N_PTS / (TKT*8);
  for (int chunk = 0; chunk < CH; ++chunk) {
    const float lthr = s_thr;
#pragma unroll
    for (int k = 0; k < 8; ++k) {
      int p = (chunk*8 + k)*TKT + tid;
      float q0 = x[p*3+0], q1 = x[p*3+1], q2 = x[p*3+2];
      float dot  = fmaf(cz,q2, fmaf(cy,q1, cx*q0));
      float pp   = fmaf(q2,q2, fmaf(q1,q1, q0*q0));
      float dist = fmaf(-2.0f, dot, c2) + pp;
      if (dist <= lthr) {
        int pos = atomicAdd(&s_cnt, 1);
        cv[pos] = dist; ci[pos] = p;
      }
    }
    __syncthreads();
    const int n = s_cnt;
    const bool last = (chunk == CH-1);
    if (n > (CAP - TKT*8) || last) {
      if (tid < 64) {
        for (int it = 0; it < K_NB; ++it) {
          unsigned long long lk = ~0ull;
          for (int j = tid; j < n; j += 64) {
            unsigned long long kk = packMinKey(cv[j], (unsigned)ci[j]);
            if (kk < lk) lk = kk;
          }
#pragma unroll
          for (int off = 32; off; off >>= 1) {
            unsigned long long o = __shfl_xor(lk, off);
            if (o < lk) lk = o;
          }
          const int mi = (int)(unsigned int)(lk & 0xFFFFFFFFull);
          for (int j = tid; j < n; j += 64)
            if (ci[j] == mi) cv[j] = __builtin_inff();
          if (tid == 0) { selv[it] = unpackMinVal(lk); seli[it] = mi; }
        }
      }
      __syncthreads();
      if (!last) {
        if (tid < K_NB) { cv[tid] = selv[tid]; ci[tid] = seli[tid]; }
        if (tid == 0)   { s_cnt = K_NB; s_thr = selv[K_NB-1]; }
        __syncthreads();
      }
    }
  }

  const long base = (long)g * (K_NB*F_DIM);
#pragma unroll
  for (int m = 0; m < (K_NB*F_DIM)/TKT; ++m) {
    int lin = m*TKT + tid;
    int j = lin >> 6, c = lin & 63;
    out[base + lin] = feat[(long)seli[j]*F_DIM + c];
  }
}

// ---------- Phase 3: per-point argmin over 1024 centers (proven) ----------
__global__ void __launch_bounds__(256)
argmin_kernel(const float* __restrict__ x, const float* __restrict__ centers,
              float* __restrict__ outIdx)
{
  __shared__ float scx[N_GRP], scy[N_GRP], scz[N_GRP], sc2[N_GRP];
  for (int i = threadIdx.x; i < N_GRP; i += 256) {
    float a = centers[i*3+0], b = centers[i*3+1], c = centers[i*3+2];
    scx[i]=a; scy[i]=b; scz[i]=c;
    sc2[i] = fmaf(c,c, fmaf(b,b, a*a));
  }
  __syncthreads();
  const int p = blockIdx.x*256 + threadIdx.x;
  const float q0 = x[p*3+0], q1 = x[p*3+1], q2 = x[p*3+2];
  const float pp = fmaf(q2,q2, fmaf(q1,q1, q0*q0));
  float best = __builtin_inff(); int bi = 0;
#pragma unroll 4
  for (int c = 0; c < N_GRP; ++c) {
    float dot  = fmaf(scz[c],q2, fmaf(scy[c],q1, scx[c]*q0));
    float dist = fmaf(-2.0f, dot, sc2[c]) + pp;
    if (dist < best) { best = dist; bi = c; }
  }
  outIdx[p] = (float)bi;
}

// ---------- launch ----------
extern "C" void kernel_launch(void* const* d_in, const int* in_sizes, int n_in,
                              void* d_out, int out_size, void* d_ws, size_t ws_size,
                              hipStream_t stream)
{
  const float* x    = (const float*)d_in[0];
  const float* feat = (const float*)d_in[1];
  float* out = (float*)d_out;
  char* ws = (char*)d_ws;

  float* ctr = (float*)ws;                                   // 12 KiB centers @ 0
  const size_t DD_OFF  = 65536;                              // 256 KiB d array
  const size_t XS_OFF  = DD_OFF + (size_t)N_PTS*4;           // 1 MiB float4 pts
  const size_t NEED    = XS_OFF + (size_t)N_PTS*16;

  if (ws_size >= NEED) {
    float*  dd  = (float*)(ws + DD_OFF);
    float4* xs4 = (float4*)(ws + XS_OFF);
    hipLaunchKernelGGL(fps_kernel, dim3(1), dim3(FPS1_THR), 0, stream, x, xs4, dd, ctr);
  } else {
    unsigned long long* slots = (unsigned long long*)(ws + 16384);
    unsigned int*       cnts  = (unsigned int*)(ws + 24576);
    hipMemsetAsync(ws + 16384, 0, 12288, stream);
    hipLaunchKernelGGL(fps_safe_kernel, dim3(F2_BLOCKS), dim3(F2_THR), 0, stream,
                       x, slots, cnts, ctr);
  }
  hipLaunchKernelGGL(topk_kernel, dim3(N_GRP), dim3(TKT), 0, stream, x, feat, ctr, out);
  hipLaunchKernelGGL(argmin_kernel, dim3(N_PTS/256), dim3(256), 0, stream,
                     x, ctr, out + (size_t)N_GRP*K_NB*F_DIM);
}

// Round 12
// 3095.856 us; speedup vs baseline: 6.5293x; 6.5293x over previous
//
#include <hip/hip_runtime.h>
#include <stdint.h>

#define N_PTS   65536
#define N_GRP   1024
#define K_NB    32
#define F_DIM   64

// ---- FPS (single block, static interleaved chunk ownership) ----
#define FPS1_THR 1024
#define NCHUNK   1024
#define CPTS     64
#define NBINS    4096        // 16x16x16 morton grid

// ---- fallback FPS (R1-proven agent-scope), only if ws too small ----
#define F2_BLOCKS 16
#define F2_THR    512
#define F2_TT     (F2_BLOCKS*F2_THR)
#define F2_P      (N_PTS / F2_TT)

// ---------- helpers ----------
__device__ __forceinline__ unsigned long long packMinKey(float v, unsigned int idx) {
  unsigned int b = __float_as_uint(v);
  b = (b & 0x80000000u) ? ~b : (b | 0x80000000u);
  return ((unsigned long long)b << 32) | idx;
}
__device__ __forceinline__ float unpackMinVal(unsigned long long k) {
  unsigned int b = (unsigned int)(k >> 32);
  b = (b & 0x80000000u) ? (b & 0x7FFFFFFFu) : ~b;
  return __uint_as_float(b);
}
__device__ __forceinline__ unsigned spread4(unsigned b) {
  return (b & 1u) | ((b & 2u) << 2) | ((b & 4u) << 4) | ((b & 8u) << 6);
}
__device__ __forceinline__ unsigned morton_bid(float a, float b, float c) {
  const float S = 16.0f / 11.0f;
  int bx = (int)((a + 5.5f) * S);
  int by = (int)((b + 5.5f) * S);
  int bz = (int)((c + 5.5f) * S);
  bx = min(max(bx, 0), 15); by = min(max(by, 0), 15); bz = min(max(bz, 0), 15);
  return spread4((unsigned)bx) | (spread4((unsigned)by) << 1) | (spread4((unsigned)bz) << 2);
}
// key bits: dist_bits[63:32] | (0xFFFF-orig)[31:16] | chunk[9:0]
// sign bit 0, f64-NaN impossible (exponent field never all-ones) -> f64 order == u64 order.
__device__ __forceinline__ double packKeyD(float d, unsigned orig, int c) {
  unsigned long long k = ((unsigned long long)__float_as_uint(d) << 32)
                       | ((unsigned long long)(0xFFFFu - (orig & 0xFFFFu)) << 16)
                       | (unsigned long long)(unsigned)c;
  return __longlong_as_double((long long)k);
}

// ---------- Phase 1: FPS — one block; 2 barriers/round, ballot = active list ----------
__global__ void __launch_bounds__(FPS1_THR)
fps_kernel(const float* __restrict__ x, float4* __restrict__ xs4,
           float* __restrict__ dd, float* __restrict__ centers)
{
  __shared__ __align__(16) char smem[65536];
  double* ckeys = (double*)smem;                    // [0,8K)   per-chunk key (f64-packed)
  float* bxl = (float*)(smem + 8192);               // bbox arrays [8K,32K) (setup only)
  float* bxh = bxl + 1024;
  float* byl = bxl + 2048;
  float* byh = bxl + 3072;
  float* bzl = bxl + 4096;
  float* bzh = bxl + 5120;
  unsigned* sA = (unsigned*)(smem + 32768);         // scan ping [32K,48K) (setup only)
  unsigned* sB = (unsigned*)(smem + 49152);         // scan pong [48K,64K) (setup only)
  __shared__ double redd[16];

  const int tid = threadIdx.x, lane = tid & 63, wid = tid >> 6;
  const int sub = lane >> 4, li = lane & 15;
  const int cown = 16*lane + wid;                   // my chunk (mod-16 interleave)

  // ---- histogram
#pragma unroll
  for (int j = 0; j < NBINS/FPS1_THR; ++j) sA[tid + j*FPS1_THR] = 0u;
  __syncthreads();
  for (int i = tid; i < N_PTS; i += FPS1_THR) {
    float a = x[i*3+0], b = x[i*3+1], c = x[i*3+2];
    atomicAdd(&sA[morton_bid(a,b,c)], 1u);
  }
  __syncthreads();

  // ---- inclusive scan (ping-pong) -> sA; exclusive cursors -> sB
  {
    unsigned* src = sA; unsigned* dst = sB;
    for (int off = 1; off < NBINS; off <<= 1) {
#pragma unroll
      for (int j = 0; j < NBINS/FPS1_THR; ++j) {
        int i = tid + j*FPS1_THR;
        unsigned v = src[i];
        if (i >= off) v += src[i-off];
        dst[i] = v;
      }
      __syncthreads();
      unsigned* t_ = src; src = dst; dst = t_;
    }
#pragma unroll
    for (int j = 0; j < NBINS/FPS1_THR; ++j) {
      int i = tid + j*FPS1_THR;
      sB[i] = (i == 0) ? 0u : sA[i-1];
    }
    __syncthreads();
  }

  // ---- scatter (chunk-major [c][k]); init d = INIT_DIST
  for (int i = tid; i < N_PTS; i += FPS1_THR) {
    float a = x[i*3+0], b = x[i*3+1], c = x[i*3+2];
    unsigned pos = atomicAdd(&sB[morton_bid(a,b,c)], 1u);
    xs4[pos] = make_float4(a, b, c, __uint_as_float((unsigned)i));
    dd[pos]  = 1e10f;
  }
  __syncthreads();

  // ---- per-chunk bbox (wave w computes chunks 64w..64w+63, coalesced), to LDS
  for (int cc = 0; cc < 64; ++cc) {
    const int c = wid*64 + cc;
    float4 f = xs4[c*CPTS + lane];
    float xl = f.x, xh = f.x, yl = f.y, yh = f.y, zl = f.z, zh = f.z;
#pragma unroll
    for (int off = 32; off; off >>= 1) {
      xl = fminf(xl, __shfl_xor(xl, off)); xh = fmaxf(xh, __shfl_xor(xh, off));
      yl = fminf(yl, __shfl_xor(yl, off)); yh = fmaxf(yh, __shfl_xor(yh, off));
      zl = fminf(zl, __shfl_xor(zl, off)); zh = fmaxf(zh, __shfl_xor(zh, off));
    }
    if (lane == 0) { bxl[c]=xl; bxh[c]=xh; byl[c]=yl; byh[c]=yh; bzl[c]=zl; bzh[c]=zh; }
  }
  __syncthreads();
  // each thread picks up ITS chunk's bbox into registers
  const float rxl = bxl[cown], rxh = bxh[cown];
  const float ryl = byl[cown], ryh = byh[cown];
  const float rzl = bzl[cown], rzh = bzh[cown];

  float cx = x[0], cy = x[1], cz = x[2];            // c_0 = point 0
  if (tid == 0) { centers[0] = cx; centers[1] = cy; centers[2] = cz; }
  float cdmax = 1e10f;                              // own chunk's current max-d (upper bound)

  for (int r = 1; r < N_GRP; ++r) {
    // ---- A: test own chunk (registers only); ballot = this wave's active set
    float dxl = fmaxf(fmaxf(rxl - cx, cx - rxh), 0.0f);
    float dyl = fmaxf(fmaxf(ryl - cy, cy - ryh), 0.0f);
    float dzl = fmaxf(fmaxf(rzl - cz, cz - rzh), 0.0f);
    float b2 = fmaf(dzl, dzl, fmaf(dyl, dyl, dxl*dxl));
    const bool active = b2 < cdmax * 1.0001f;       // exact-safe margin
    unsigned long long m = __ballot(active);        // bit l <-> chunk 16*l + wid

    // ---- B: process own active chunks, 4 per iteration (16 lanes x 4 pts each)
    while (m) {
      int b0 = __ffsll(m) - 1; m &= m - 1;
      int b1 = -1, b2i = -1, b3 = -1;
      if (m) { b1  = __ffsll(m) - 1; m &= m - 1; }
      if (m) { b2i = __ffsll(m) - 1; m &= m - 1; }
      if (m) { b3  = __ffsll(m) - 1; m &= m - 1; }
      const int bb = (sub == 0) ? b0 : (sub == 1) ? b1 : (sub == 2) ? b2i : b3;
      const int c = (bb >= 0) ? (16*bb + wid) : -1;
      double key = 0.0;
      if (c >= 0) {
        const int cb = c*CPTS;
#pragma unroll
        for (int t = 0; t < 4; ++t) {
          const int sidx = cb + li + 16*t;
          float4 f = xs4[sidx];
          float dk = dd[sidx];
          float e0 = f.x - cx, e1 = f.y - cy, e2 = f.z - cz;
          float dist = fmaf(e2,e2, fmaf(e1,e1, e0*e0));   // proven chain
          float dn = fminf(dk, dist);
          dd[sidx] = dn;
          key = fmax(key, packKeyD(dn, __float_as_uint(f.w), c));
        }
      }
#pragma unroll
      for (int off = 1; off < 16; off <<= 1)        // 4-step f64 fmax in 16-lane group
        key = fmax(key, __shfl_xor(key, off));
      if (c >= 0 && li == 0) ckeys[c] = key;
    }
    __syncthreads();                                // S1: dd stores + ckeys writes done

    // ---- block argmax (f64 fmax) + own-cdmax refresh from the same read
    double kown = ckeys[cown];
    cdmax = __uint_as_float((unsigned)((unsigned long long)__double_as_longlong(kown) >> 32));
    double k = kown;
#pragma unroll
    for (int off = 32; off; off >>= 1) k = fmax(k, __shfl_xor(k, off));
    if (lane == 0) redd[wid] = k;
    __syncthreads();                                // S2: redd ready
    double k2 = redd[lane & 15];
#pragma unroll
    for (int off = 1; off < 16; off <<= 1) k2 = fmax(k2, __shfl_xor(k2, off));
    const unsigned long long kb = (unsigned long long)__double_as_longlong(k2);
    const unsigned orig = 0xFFFFu - (unsigned)((kb >> 16) & 0xFFFFull);
    cx = x[orig*3+0]; cy = x[orig*3+1]; cz = x[orig*3+2];  // broadcast load (L2-hot)
    if (tid == 0) { centers[r*3+0]=cx; centers[r*3+1]=cy; centers[r*3+2]=cz; }
  }
}

// ---------- fallback FPS (only if ws too small) ----------
__global__ void __launch_bounds__(F2_THR)
fps_safe_kernel(const float* __restrict__ x, unsigned long long* __restrict__ slots,
                unsigned int* __restrict__ cnts, float* __restrict__ centers)
{
  __shared__ unsigned long long red[F2_THR/64];
  const int t = blockIdx.x * F2_THR + threadIdx.x;
  float px[F2_P], py[F2_P], pz[F2_P], d[F2_P];
#pragma unroll
  for (int k = 0; k < F2_P; ++k) {
    int p = t + k * F2_TT;
    px[k] = x[p*3+0]; py[k] = x[p*3+1]; pz[k] = x[p*3+2];
    d[k] = 1e10f;
  }
  float cx = x[0], cy = x[1], cz = x[2];
  if (blockIdx.x == 0 && threadIdx.x == 0) {
    centers[0] = cx; centers[1] = cy; centers[2] = cz;
  }
  for (int r = 1; r < N_GRP; ++r) {
    unsigned long long best = 0ull;
#pragma unroll
    for (int k = 0; k < F2_P; ++k) {
      float e0 = px[k]-cx, e1 = py[k]-cy, e2 = pz[k]-cz;
      float dist = fmaf(e2,e2, fmaf(e1,e1, e0*e0));
      float dn = fminf(d[k], dist);
      d[k] = dn;
      unsigned long long pk = ((unsigned long long)__float_as_uint(dn) << 32)
                            | (0xFFFFFFFFu - (unsigned)(t + k*F2_TT));
      if (pk > best) best = pk;
    }
#pragma unroll
    for (int off = 32; off; off >>= 1) {
      unsigned long long o = __shfl_down(best, off);
      if (o > best) best = o;
    }
    const int wid = threadIdx.x >> 6;
    if ((threadIdx.x & 63) == 0) red[wid] = best;
    __syncthreads();
    if (threadIdx.x == 0) {
#pragma unroll
      for (int w = 1; w < F2_THR/64; ++w) if (red[w] > best) best = red[w];
      atomicMax(&slots[r], best);
      __hip_atomic_fetch_add(&cnts[r], 1u, __ATOMIC_RELEASE, __HIP_MEMORY_SCOPE_AGENT);
      while (__hip_atomic_load(&cnts[r], __ATOMIC_ACQUIRE, __HIP_MEMORY_SCOPE_AGENT) < F2_BLOCKS)
        __builtin_amdgcn_s_sleep(1);
      red[0] = __hip_atomic_load(&slots[r], __ATOMIC_RELAXED, __HIP_MEMORY_SCOPE_AGENT);
    }
    __syncthreads();
    const unsigned long long win = red[0];
    const int widx = (int)(0xFFFFFFFFu - (unsigned int)(win & 0xFFFFFFFFull));
    cx = x[widx*3+0]; cy = x[widx*3+1]; cz = x[widx*3+2];
    if (blockIdx.x == 0 && threadIdx.x == 0) {
      centers[r*3+0] = cx; centers[r*3+1] = cy; centers[r*3+2] = cz;
    }
    __syncthreads();
  }
}

// ---------- Phase 2: per-group exact 32 smallest (proven) ----------
#define TKT 256
#define CAP 3072

__global__ void __launch_bounds__(TKT)
topk_kernel(const float* __restrict__ x, const float* __restrict__ feat,
            const float* __restrict__ centers, float* __restrict__ out)
{
  __shared__ float cv[CAP];
  __shared__ int   ci[CAP];
  __shared__ int   s_cnt;
  __shared__ float s_thr;
  __shared__ float selv[K_NB];
  __shared__ int   seli[K_NB];

  const int g = blockIdx.x, tid = threadIdx.x;
  const float cx = centers[g*3+0], cy = centers[g*3+1], cz = centers[g*3+2];
  const float c2 = fmaf(cz,cz, fmaf(cy,cy, cx*cx));
  if (tid == 0) { s_cnt = 0; s_thr = __builtin_inff(); }
  __syncthreads();

  const int CH = N_PTS / (TKT*8);
  for (int chunk = 0; chunk < CH; ++chunk) {
    const float lthr = s_thr;
#pragma unroll
    for (int k = 0; k < 8; ++k) {
      int p = (chunk*8 + k)*TKT + tid;
      float q0 = x[p*3+0], q1 = x[p*3+1], q2 = x[p*3+2];
      float dot  = fmaf(cz,q2, fmaf(cy,q1, cx*q0));
      float pp   = fmaf(q2,q2, fmaf(q1,q1, q0*q0));
      float dist = fmaf(-2.0f, dot, c2) + pp;
      if (dist <= lthr) {
        int pos = atomicAdd(&s_cnt, 1);
        cv[pos] = dist; ci[pos] = p;
      }
    }
    __syncthreads();
    const int n = s_cnt;
    const bool last = (chunk == CH-1);
    if (n > (CAP - TKT*8) || last) {
      if (tid < 64) {
        for (int it = 0; it < K_NB; ++it) {
          unsigned long long lk = ~0ull;
          for (int j = tid; j < n; j += 64) {
            unsigned long long kk = packMinKey(cv[j], (unsigned)ci[j]);
            if (kk < lk) lk = kk;
          }
#pragma unroll
          for (int off = 32; off; off >>= 1) {
            unsigned long long o = __shfl_xor(lk, off);
            if (o < lk) lk = o;
          }
          const int mi = (int)(unsigned int)(lk & 0xFFFFFFFFull);
          for (int j = tid; j < n; j += 64)
            if (ci[j] == mi) cv[j] = __builtin_inff();
          if (tid == 0) { selv[it] = unpackMinVal(lk); seli[it] = mi; }
        }
      }
      __syncthreads();
      if (!last) {
        if (tid < K_NB) { cv[tid] = selv[tid]; ci[tid] = seli[tid]; }
        if (tid == 0)   { s_cnt = K_NB; s_thr = selv[K_NB-1]; }
        __syncthreads();
      }
    }
  }

  const long base = (long)g * (K_NB*F_DIM);
#pragma unroll
  for (int m = 0; m < (K_NB*F_DIM)/TKT; ++m) {
    int lin = m*TKT + tid;
    int j = lin >> 6, c = lin & 63;
    out[base + lin] = feat[(long)seli[j]*F_DIM + c];
  }
}

// ---------- Phase 3: per-point argmin over 1024 centers (proven) ----------
__global__ void __launch_bounds__(256)
argmin_kernel(const float* __restrict__ x, const float* __restrict__ centers,
              float* __restrict__ outIdx)
{
  __shared__ float scx[N_GRP], scy[N_GRP], scz[N_GRP], sc2[N_GRP];
  for (int i = threadIdx.x; i < N_GRP; i += 256) {
    float a = centers[i*3+0], b = centers[i*3+1], c = centers[i*3+2];
    scx[i]=a; scy[i]=b; scz[i]=c;
    sc2[i] = fmaf(c,c, fmaf(b,b, a*a));
  }
  __syncthreads();
  const int p = blockIdx.x*256 + threadIdx.x;
  const float q0 = x[p*3+0], q1 = x[p*3+1], q2 = x[p*3+2];
  const float pp = fmaf(q2,q2, fmaf(q1,q1, q0*q0));
  float best = __builtin_inff(); int bi = 0;
#pragma unroll 4
  for (int c = 0; c < N_GRP; ++c) {
    float dot  = fmaf(scz[c],q2, fmaf(scy[c],q1, scx[c]*q0));
    float dist = fmaf(-2.0f, dot, sc2[c]) + pp;
    if (dist < best) { best = dist; bi = c; }
  }
  outIdx[p] = (float)bi;
}

// ---------- launch ----------
extern "C" void kernel_launch(void* const* d_in, const int* in_sizes, int n_in,
                              void* d_out, int out_size, void* d_ws, size_t ws_size,
                              hipStream_t stream)
{
  const float* x    = (const float*)d_in[0];
  const float* feat = (const float*)d_in[1];
  float* out = (float*)d_out;
  char* ws = (char*)d_ws;

  float* ctr = (float*)ws;                                   // 12 KiB centers @ 0
  const size_t DD_OFF  = 65536;                              // 256 KiB d array
  const size_t XS_OFF  = DD_OFF + (size_t)N_PTS*4;           // 1 MiB float4 pts
  const size_t NEED    = XS_OFF + (size_t)N_PTS*16;

  if (ws_size >= NEED) {
    float*  dd  = (float*)(ws + DD_OFF);
    float4* xs4 = (float4*)(ws + XS_OFF);
    hipLaunchKernelGGL(fps_kernel, dim3(1), dim3(FPS1_THR), 0, stream, x, xs4, dd, ctr);
  } else {
    unsigned long long* slots = (unsigned long long*)(ws + 16384);
    unsigned int*       cnts  = (unsigned int*)(ws + 24576);
    hipMemsetAsync(ws + 16384, 0, 12288, stream);
    hipLaunchKernelGGL(fps_safe_kernel, dim3(F2_BLOCKS), dim3(F2_THR), 0, stream,
                       x, slots, cnts, ctr);
  }
  hipLaunchKernelGGL(topk_kernel, dim3(N_GRP), dim3(TKT), 0, stream, x, feat, ctr, out);
  hipLaunchKernelGGL(argmin_kernel, dim3(N_PTS/256), dim3(256), 0, stream,
                     x, ctr, out + (size_t)N_GRP*K_NB*F_DIM);
}